// Round 1
// baseline (657.404 us; speedup 1.0000x reference)
//
#include <hip/hip_runtime.h>
#include <math.h>

#define NN 100000
#define NE 1600000
#define IC 128
#define OC 64
#define NEG_SLOPE 0.2f
#define EPS_F 1e-10f

// ---------------- h = x @ W^T ----------------
// block: 256 threads, covers 64 oc x 64 nodes; each thread 4 oc x 4 nodes.
__global__ __launch_bounds__(256) void linear_kernel(
    const float* __restrict__ x, const float* __restrict__ W,
    float* __restrict__ h)
{
    __shared__ float Ws[64 * 129];
    __shared__ float xs[64 * 129];
    const int tid = threadIdx.x;
    const int n0 = blockIdx.x * 64;

    for (int i = tid; i < 64 * 128; i += 256) {
        int r = i >> 7, c = i & 127;
        Ws[r * 129 + c] = W[i];
    }
    for (int i = tid; i < 64 * 128; i += 256) {
        int r = i >> 7, c = i & 127;
        int n = n0 + r;
        xs[r * 129 + c] = (n < NN) ? x[n * IC + c] : 0.f;
    }
    __syncthreads();

    const int og = tid >> 4;  // 0..15 -> oc base og*4
    const int ng = tid & 15;  // node base ng*4
    float acc[4][4];
#pragma unroll
    for (int i = 0; i < 4; i++)
#pragma unroll
        for (int j = 0; j < 4; j++) acc[i][j] = 0.f;

#pragma unroll 4
    for (int k = 0; k < 128; k++) {
        float wv[4], xv[4];
#pragma unroll
        for (int i = 0; i < 4; i++) wv[i] = Ws[(og * 4 + i) * 129 + k];
#pragma unroll
        for (int j = 0; j < 4; j++) xv[j] = xs[(ng * 4 + j) * 129 + k];
#pragma unroll
        for (int i = 0; i < 4; i++)
#pragma unroll
            for (int j = 0; j < 4; j++) acc[i][j] += wv[i] * xv[j];
    }

#pragma unroll
    for (int j = 0; j < 4; j++) {
        int n = n0 + ng * 4 + j;
        if (n < NN) {
#pragma unroll
            for (int i = 0; i < 4; i++) h[n * OC + og * 4 + i] = acc[i][j];
        }
    }
}

// ---------------- e_l = h @ a_l, e_r = h @ a_r ----------------
// one wave per node, lane = channel
__global__ __launch_bounds__(256) void ev_kernel(
    const float* __restrict__ h, const float* __restrict__ a_l,
    const float* __restrict__ a_r, float* __restrict__ e_l,
    float* __restrict__ e_r)
{
    const int node = blockIdx.x * 4 + (threadIdx.x >> 6);
    const int lane = threadIdx.x & 63;
    if (node >= NN) return;
    float hv = h[node * OC + lane];
    float pl = hv * a_l[lane];
    float pr = hv * a_r[lane];
#pragma unroll
    for (int off = 32; off > 0; off >>= 1) {
        pl += __shfl_down(pl, off);
        pr += __shfl_down(pr, off);
    }
    if (lane == 0) {
        e_l[node] = pl;
        e_r[node] = pr;
    }
}

// ---------------- degree count ----------------
__global__ __launch_bounds__(256) void degree_kernel(
    const int* __restrict__ dst, int* __restrict__ deg)
{
    int e = blockIdx.x * 256 + threadIdx.x;
    if (e < NE) atomicAdd(&deg[dst[e]], 1);
}

// ---------------- single-block exclusive scan ----------------
__global__ __launch_bounds__(1024) void scan_kernel(
    const int* __restrict__ deg, int* __restrict__ offsets)
{
    __shared__ int sums[1024];
    const int t = threadIdx.x;
    const int CH = (NN + 1023) / 1024;
    int begin = t * CH;
    int end = begin + CH;
    if (begin > NN) begin = NN;
    if (end > NN) end = NN;
    int s = 0;
    for (int i = begin; i < end; i++) s += deg[i];
    sums[t] = s;
    __syncthreads();
    for (int off = 1; off < 1024; off <<= 1) {
        int v = (t >= off) ? sums[t - off] : 0;
        __syncthreads();
        sums[t] += v;
        __syncthreads();
    }
    int base = (t > 0) ? sums[t - 1] : 0;
    int running = base;
    for (int i = begin; i < end; i++) {
        offsets[i] = running;
        running += deg[i];
    }
    if (end == NN && begin < NN) offsets[NN] = running;
}

// ---------------- scatter edges into CSR ----------------
__global__ __launch_bounds__(256) void scatter_kernel(
    const int* __restrict__ src, const int* __restrict__ dst,
    const int* __restrict__ offsets, int* __restrict__ cursor,
    int* __restrict__ sorted_src)
{
    int e = blockIdx.x * 256 + threadIdx.x;
    if (e >= NE) return;
    int d = dst[e];
    int p = atomicAdd(&cursor[d], 1);
    sorted_src[offsets[d] + p] = src[e];
}

// ---------------- softmax + aggregate: one wave per dst node ----------------
__global__ __launch_bounds__(256) void aggregate_kernel(
    const float* __restrict__ h, const float* __restrict__ e_l,
    const float* __restrict__ e_r, const int* __restrict__ offsets,
    const int* __restrict__ sorted_src, const float* __restrict__ bias,
    float* __restrict__ out)
{
    const int node = blockIdx.x * 4 + (threadIdx.x >> 6);
    const int lane = threadIdx.x & 63;
    if (node >= NN) return;
    const int start = offsets[node];
    const int end = offsets[node + 1];
    const float el = e_l[node];

    // pass 1: segment max (lane-parallel)
    float m = -INFINITY;
    for (int j = start + lane; j < end; j += 64) {
        int s = sorted_src[j];
        float a = el + e_r[s];
        a = (a > 0.f) ? a : NEG_SLOPE * a;
        m = fmaxf(m, a);
    }
#pragma unroll
    for (int off = 32; off > 0; off >>= 1) m = fmaxf(m, __shfl_down(m, off));
    m = __shfl(m, 0);

    // pass 2: exp-sum + weighted accumulate (scalar edge loop, coalesced h row)
    float sum = 0.f, acc = 0.f;
    for (int j = start; j < end; j++) {
        int s = sorted_src[j];
        float a = el + e_r[s];
        a = (a > 0.f) ? a : NEG_SLOPE * a;
        float w = __expf(a - m);
        sum += w;
        acc += w * h[s * OC + lane];
    }
    out[node * OC + lane] = acc / (sum + EPS_F) + bias[lane];
}

extern "C" void kernel_launch(void* const* d_in, const int* in_sizes, int n_in,
                              void* d_out, int out_size, void* d_ws, size_t ws_size,
                              hipStream_t stream)
{
    const float* x = (const float*)d_in[0];
    const int* edge_index = (const int*)d_in[1];
    const float* W = (const float*)d_in[2];
    const float* a_l = (const float*)d_in[3];
    const float* a_r = (const float*)d_in[4];
    const float* bias = (const float*)d_in[5];
    float* out = (float*)d_out;

    const int* src = edge_index;       // row 0
    const int* dst = edge_index + NE;  // row 1

    // workspace layout (all 4-byte elements)
    char* w = (char*)d_ws;
    float* h = (float*)w;                     // NN*OC
    size_t off = (size_t)NN * OC * 4;
    float* e_l = (float*)(w + off); off += (size_t)NN * 4;
    float* e_r = (float*)(w + off); off += (size_t)NN * 4;
    int* deg = (int*)(w + off);     off += (size_t)NN * 4;
    int* cursor = (int*)(w + off);  off += (size_t)NN * 4;   // adjacent to deg: one memset
    int* offsets = (int*)(w + off); off += (size_t)(NN + 1) * 4;
    int* sorted_src = (int*)(w + off);

    // zero deg + cursor (ws is poisoned 0xAA before every timed launch)
    hipMemsetAsync(deg, 0, (size_t)NN * 2 * 4, stream);

    linear_kernel<<<(NN + 63) / 64, 256, 0, stream>>>(x, W, h);
    ev_kernel<<<(NN + 3) / 4, 256, 0, stream>>>(h, a_l, a_r, e_l, e_r);
    degree_kernel<<<(NE + 255) / 256, 256, 0, stream>>>(dst, deg);
    scan_kernel<<<1, 1024, 0, stream>>>(deg, offsets);
    scatter_kernel<<<(NE + 255) / 256, 256, 0, stream>>>(src, dst, offsets, cursor, sorted_src);
    aggregate_kernel<<<(NN + 3) / 4, 256, 0, stream>>>(h, e_l, e_r, offsets, sorted_src, bias, out);
}

// Round 2
// 396.846 us; speedup vs baseline: 1.6566x; 1.6566x over previous
//
#include <hip/hip_runtime.h>
#include <math.h>

#define NN 100000
#define NE 1600000
#define IC 128
#define OC 64
#define NEG_SLOPE 0.2f
#define EPS_F 1e-10f

// Swizzled LDS word index for a [row][128-float] tile stored as 32 float4 chunks/row.
// chunk = c4 ^ (row>>2): W-reads (rows og*4+i) -> 4 distinct addrs, distinct bank
// groups; x-reads (rows ng*4+j) -> 16 distinct chunks, 2-way (free). 16B-aligned.
__device__ __forceinline__ int swz(int row, int c4) {
    return row * 128 + (((c4 ^ (row >> 2)) & 31) << 2);
}

// ---------------- h = x @ W^T ----------------
// 64 nodes x 64 oc per block; thread = 4 oc x 4 nodes; float4 LDS reads.
__global__ __launch_bounds__(256) void linear_kernel(
    const float* __restrict__ x, const float* __restrict__ W,
    float* __restrict__ h)
{
    __shared__ float Ws[64 * 128];
    __shared__ float xs[64 * 128];
    const int tid = threadIdx.x;
    const int n0 = blockIdx.x * 64;

#pragma unroll
    for (int it = 0; it < 8; it++) {
        int idx4 = it * 256 + tid;          // 2048 float4 chunks per tile
        int r = idx4 >> 5, c4 = idx4 & 31;
        float4 wv = *(const float4*)&W[r * 128 + (c4 << 2)];
        *(float4*)&Ws[swz(r, c4)] = wv;
        int n = n0 + r;
        float4 xv = make_float4(0.f, 0.f, 0.f, 0.f);
        if (n < NN) xv = *(const float4*)&x[(size_t)n * 128 + (c4 << 2)];
        *(float4*)&xs[swz(r, c4)] = xv;
    }
    __syncthreads();

    const int og = tid >> 4;  // oc base og*4
    const int ng = tid & 15;  // node base ng*4
    float acc[4][4];
#pragma unroll
    for (int i = 0; i < 4; i++)
#pragma unroll
        for (int j = 0; j < 4; j++) acc[i][j] = 0.f;

#pragma unroll 4
    for (int k4 = 0; k4 < 32; k4++) {
        float4 wv[4], xv[4];
#pragma unroll
        for (int i = 0; i < 4; i++) wv[i] = *(const float4*)&Ws[swz(og * 4 + i, k4)];
#pragma unroll
        for (int j = 0; j < 4; j++) xv[j] = *(const float4*)&xs[swz(ng * 4 + j, k4)];
#pragma unroll
        for (int i = 0; i < 4; i++)
#pragma unroll
            for (int j = 0; j < 4; j++) {
                acc[i][j] += wv[i].x * xv[j].x;
                acc[i][j] += wv[i].y * xv[j].y;
                acc[i][j] += wv[i].z * xv[j].z;
                acc[i][j] += wv[i].w * xv[j].w;
            }
    }

#pragma unroll
    for (int j = 0; j < 4; j++) {
        int n = n0 + ng * 4 + j;
        if (n < NN) {
            float4 o = make_float4(acc[0][j], acc[1][j], acc[2][j], acc[3][j]);
            *(float4*)&h[(size_t)n * OC + og * 4] = o;
        }
    }
}

// ---------------- e_l = h @ a_l, e_r = h @ a_r ----------------
__global__ __launch_bounds__(256) void ev_kernel(
    const float* __restrict__ h, const float* __restrict__ a_l,
    const float* __restrict__ a_r, float* __restrict__ e_l,
    float* __restrict__ e_r)
{
    const int node = blockIdx.x * 4 + (threadIdx.x >> 6);
    const int lane = threadIdx.x & 63;
    if (node >= NN) return;
    float hv = h[(size_t)node * OC + lane];
    float pl = hv * a_l[lane];
    float pr = hv * a_r[lane];
#pragma unroll
    for (int off = 32; off > 0; off >>= 1) {
        pl += __shfl_down(pl, off);
        pr += __shfl_down(pr, off);
    }
    if (lane == 0) {
        e_l[node] = pl;
        e_r[node] = pr;
    }
}

// ---------------- degree count (int4 loads) ----------------
__global__ __launch_bounds__(256) void degree_kernel(
    const int* __restrict__ dst, int* __restrict__ deg)
{
    int i = blockIdx.x * 256 + threadIdx.x;   // int4 group index, NE % 4 == 0
    if (i < NE / 4) {
        int4 d = ((const int4*)dst)[i];
        atomicAdd(&deg[d.x], 1);
        atomicAdd(&deg[d.y], 1);
        atomicAdd(&deg[d.z], 1);
        atomicAdd(&deg[d.w], 1);
    }
}

// ---------------- 3-phase multi-block scan ----------------
__global__ __launch_bounds__(1024) void scan_block_kernel(
    const int* __restrict__ deg, int* __restrict__ offsets,
    int* __restrict__ bsums)
{
    __shared__ int s[1024];
    const int t = threadIdx.x;
    const int i = blockIdx.x * 1024 + t;
    int v = (i < NN) ? deg[i] : 0;
    s[t] = v;
    __syncthreads();
    for (int off = 1; off < 1024; off <<= 1) {
        int u = (t >= off) ? s[t - off] : 0;
        __syncthreads();
        s[t] += u;
        __syncthreads();
    }
    if (i < NN) offsets[i] = s[t] - v;  // block-local exclusive
    if (t == 1023) bsums[blockIdx.x] = s[1023];
}

__global__ __launch_bounds__(128) void scan_bsums_kernel(
    int* __restrict__ bsums, int* __restrict__ offsets)
{
    __shared__ int s[128];
    const int t = threadIdx.x;
    const int NB = (NN + 1023) / 1024;  // 98
    int v = (t < NB) ? bsums[t] : 0;
    s[t] = v;
    __syncthreads();
    for (int off = 1; off < 128; off <<= 1) {
        int u = (t >= off) ? s[t - off] : 0;
        __syncthreads();
        s[t] += u;
        __syncthreads();
    }
    if (t < NB) bsums[t] = s[t] - v;    // exclusive block offsets
    if (t == NB - 1) offsets[NN] = s[t];
}

__global__ __launch_bounds__(1024) void scan_add_kernel(
    int* __restrict__ offsets, const int* __restrict__ bsums)
{
    int i = blockIdx.x * 1024 + threadIdx.x;
    if (i < NN) offsets[i] += bsums[blockIdx.x];
}

// ---------------- scatter edges into CSR + precompute softmax weights ----------------
__global__ __launch_bounds__(256) void scatter_kernel(
    const int* __restrict__ src, const int* __restrict__ dst,
    const float* __restrict__ e_l, const float* __restrict__ e_r,
    const int* __restrict__ offsets, int* __restrict__ cursor,
    int* __restrict__ sorted_src, float* __restrict__ sorted_w)
{
    int e = blockIdx.x * 256 + threadIdx.x;
    if (e >= NE) return;
    int d = dst[e];
    int s = src[e];
    float a = e_l[d] + e_r[s];
    a = (a > 0.f) ? a : NEG_SLOPE * a;
    float w = __expf(a);                // no max-shift: |a| <= ~8, exp safe in fp32
    int p = atomicAdd(&cursor[d], 1);
    int pos = offsets[d] + p;
    sorted_src[pos] = s;
    sorted_w[pos] = w;
}

// ---------------- softmax-normalize + aggregate: one wave per dst node ----------------
__global__ __launch_bounds__(256) void aggregate_kernel(
    const float* __restrict__ h, const int* __restrict__ offsets,
    const int* __restrict__ sorted_src, const float* __restrict__ sorted_w,
    const float* __restrict__ bias, float* __restrict__ out)
{
    const int node = blockIdx.x * 4 + (threadIdx.x >> 6);
    const int lane = threadIdx.x & 63;
    if (node >= NN) return;
    const int start = offsets[node];
    const int end = offsets[node + 1];

    // lane-parallel weight sum (coalesced)
    float sum = 0.f;
    for (int j = start + lane; j < end; j += 64) sum += sorted_w[j];
#pragma unroll
    for (int off = 32; off > 0; off >>= 1) sum += __shfl_xor(sum, off);

    // weighted accumulate, unroll x4 for outstanding gathers
    float acc = 0.f;
    int j = start;
    for (; j + 3 < end; j += 4) {
        int s0 = sorted_src[j], s1 = sorted_src[j + 1];
        int s2 = sorted_src[j + 2], s3 = sorted_src[j + 3];
        float w0 = sorted_w[j], w1 = sorted_w[j + 1];
        float w2 = sorted_w[j + 2], w3 = sorted_w[j + 3];
        float h0 = h[(size_t)s0 * OC + lane];
        float h1 = h[(size_t)s1 * OC + lane];
        float h2 = h[(size_t)s2 * OC + lane];
        float h3 = h[(size_t)s3 * OC + lane];
        acc += w0 * h0;
        acc += w1 * h1;
        acc += w2 * h2;
        acc += w3 * h3;
    }
    for (; j < end; j++) acc += sorted_w[j] * h[(size_t)sorted_src[j] * OC + lane];

    out[(size_t)node * OC + lane] = acc / (sum + EPS_F) + bias[lane];
}

extern "C" void kernel_launch(void* const* d_in, const int* in_sizes, int n_in,
                              void* d_out, int out_size, void* d_ws, size_t ws_size,
                              hipStream_t stream)
{
    const float* x = (const float*)d_in[0];
    const int* edge_index = (const int*)d_in[1];
    const float* W = (const float*)d_in[2];
    const float* a_l = (const float*)d_in[3];
    const float* a_r = (const float*)d_in[4];
    const float* bias = (const float*)d_in[5];
    float* out = (float*)d_out;

    const int* src = edge_index;       // row 0
    const int* dst = edge_index + NE;  // row 1

    // workspace layout
    char* w = (char*)d_ws;
    float* h = (float*)w;                      // NN*OC
    size_t off = (size_t)NN * OC * 4;
    float* e_l = (float*)(w + off); off += (size_t)NN * 4;
    float* e_r = (float*)(w + off); off += (size_t)NN * 4;
    int* deg = (int*)(w + off);     off += (size_t)NN * 4;
    int* cursor = (int*)(w + off);  off += (size_t)NN * 4;  // adjacent to deg: one memset
    int* offsets = (int*)(w + off); off += (size_t)(NN + 1) * 4;
    int* bsums = (int*)(w + off);   off += 128 * 4;
    int* sorted_src = (int*)(w + off); off += (size_t)NE * 4;
    float* sorted_w = (float*)(w + off);

    hipMemsetAsync(deg, 0, (size_t)NN * 2 * 4, stream);

    linear_kernel<<<(NN + 63) / 64, 256, 0, stream>>>(x, W, h);
    ev_kernel<<<(NN + 3) / 4, 256, 0, stream>>>(h, a_l, a_r, e_l, e_r);
    degree_kernel<<<(NE / 4 + 255) / 256, 256, 0, stream>>>(dst, deg);
    scan_block_kernel<<<(NN + 1023) / 1024, 1024, 0, stream>>>(deg, offsets, bsums);
    scan_bsums_kernel<<<1, 128, 0, stream>>>(bsums, offsets);
    scan_add_kernel<<<(NN + 1023) / 1024, 1024, 0, stream>>>(offsets, bsums);
    scatter_kernel<<<(NE + 255) / 256, 256, 0, stream>>>(src, dst, e_l, e_r, offsets, cursor,
                                                         sorted_src, sorted_w);
    aggregate_kernel<<<(NN + 3) / 4, 256, 0, stream>>>(h, offsets, sorted_src, sorted_w, bias, out);
}

// Round 3
// 360.216 us; speedup vs baseline: 1.8250x; 1.1017x over previous
//
#include <hip/hip_runtime.h>
#include <math.h>

#define NN 100000
#define NE 1600000
#define IC 128
#define OC 64
#define NEG_SLOPE 0.2f
#define EPS_F 1e-10f

// Swizzled LDS word index for a [row][128-float] tile stored as 32 float4 chunks/row.
__device__ __forceinline__ int swz(int row, int c4) {
    return row * 128 + (((c4 ^ (row >> 2)) & 31) << 2);
}

// ---------------- h = x @ W^T ----------------
__global__ __launch_bounds__(256) void linear_kernel(
    const float* __restrict__ x, const float* __restrict__ W,
    float* __restrict__ h)
{
    __shared__ float Ws[64 * 128];
    __shared__ float xs[64 * 128];
    const int tid = threadIdx.x;
    const int n0 = blockIdx.x * 64;

#pragma unroll
    for (int it = 0; it < 8; it++) {
        int idx4 = it * 256 + tid;
        int r = idx4 >> 5, c4 = idx4 & 31;
        float4 wv = *(const float4*)&W[r * 128 + (c4 << 2)];
        *(float4*)&Ws[swz(r, c4)] = wv;
        int n = n0 + r;
        float4 xv = make_float4(0.f, 0.f, 0.f, 0.f);
        if (n < NN) xv = *(const float4*)&x[(size_t)n * 128 + (c4 << 2)];
        *(float4*)&xs[swz(r, c4)] = xv;
    }
    __syncthreads();

    const int og = tid >> 4;
    const int ng = tid & 15;
    float acc[4][4];
#pragma unroll
    for (int i = 0; i < 4; i++)
#pragma unroll
        for (int j = 0; j < 4; j++) acc[i][j] = 0.f;

#pragma unroll 4
    for (int k4 = 0; k4 < 32; k4++) {
        float4 wv[4], xv[4];
#pragma unroll
        for (int i = 0; i < 4; i++) wv[i] = *(const float4*)&Ws[swz(og * 4 + i, k4)];
#pragma unroll
        for (int j = 0; j < 4; j++) xv[j] = *(const float4*)&xs[swz(ng * 4 + j, k4)];
#pragma unroll
        for (int i = 0; i < 4; i++)
#pragma unroll
            for (int j = 0; j < 4; j++) {
                acc[i][j] += wv[i].x * xv[j].x;
                acc[i][j] += wv[i].y * xv[j].y;
                acc[i][j] += wv[i].z * xv[j].z;
                acc[i][j] += wv[i].w * xv[j].w;
            }
    }

#pragma unroll
    for (int j = 0; j < 4; j++) {
        int n = n0 + ng * 4 + j;
        if (n < NN) {
            float4 o = make_float4(acc[0][j], acc[1][j], acc[2][j], acc[3][j]);
            *(float4*)&h[(size_t)n * OC + og * 4] = o;
        }
    }
}

// ---------------- e_l = h @ a_l, e_r = h @ a_r ----------------
__global__ __launch_bounds__(256) void ev_kernel(
    const float* __restrict__ h, const float* __restrict__ a_l,
    const float* __restrict__ a_r, float* __restrict__ e_l,
    float* __restrict__ e_r)
{
    const int node = blockIdx.x * 4 + (threadIdx.x >> 6);
    const int lane = threadIdx.x & 63;
    if (node >= NN) return;
    float hv = h[(size_t)node * OC + lane];
    float pl = hv * a_l[lane];
    float pr = hv * a_r[lane];
#pragma unroll
    for (int off = 32; off > 0; off >>= 1) {
        pl += __shfl_down(pl, off);
        pr += __shfl_down(pr, off);
    }
    if (lane == 0) {
        e_l[node] = pl;
        e_r[node] = pr;
    }
}

// ---------------- degree count (int4 loads) ----------------
__global__ __launch_bounds__(256) void degree_kernel(
    const int* __restrict__ dst, int* __restrict__ deg)
{
    int i = blockIdx.x * 256 + threadIdx.x;
    if (i < NE / 4) {
        int4 d = ((const int4*)dst)[i];
        atomicAdd(&deg[d.x], 1);
        atomicAdd(&deg[d.y], 1);
        atomicAdd(&deg[d.z], 1);
        atomicAdd(&deg[d.w], 1);
    }
}

// ---------------- 3-phase multi-block scan ----------------
__global__ __launch_bounds__(1024) void scan_block_kernel(
    const int* __restrict__ deg, int* __restrict__ offsets,
    int* __restrict__ bsums)
{
    __shared__ int s[1024];
    const int t = threadIdx.x;
    const int i = blockIdx.x * 1024 + t;
    int v = (i < NN) ? deg[i] : 0;
    s[t] = v;
    __syncthreads();
    for (int off = 1; off < 1024; off <<= 1) {
        int u = (t >= off) ? s[t - off] : 0;
        __syncthreads();
        s[t] += u;
        __syncthreads();
    }
    if (i < NN) offsets[i] = s[t] - v;
    if (t == 1023) bsums[blockIdx.x] = s[1023];
}

__global__ __launch_bounds__(128) void scan_bsums_kernel(
    int* __restrict__ bsums, int* __restrict__ offsets)
{
    __shared__ int s[128];
    const int t = threadIdx.x;
    const int NB = (NN + 1023) / 1024;
    int v = (t < NB) ? bsums[t] : 0;
    s[t] = v;
    __syncthreads();
    for (int off = 1; off < 128; off <<= 1) {
        int u = (t >= off) ? s[t - off] : 0;
        __syncthreads();
        s[t] += u;
        __syncthreads();
    }
    if (t < NB) bsums[t] = s[t] - v;
    if (t == NB - 1) offsets[NN] = s[t];
}

// also seeds cursor[i] = final offsets[i] so scatter's atomicAdd returns absolute pos
__global__ __launch_bounds__(1024) void scan_add_kernel(
    int* __restrict__ offsets, const int* __restrict__ bsums,
    int* __restrict__ cursor)
{
    int i = blockIdx.x * 1024 + threadIdx.x;
    if (i < NN) {
        int v = offsets[i] + bsums[blockIdx.x];
        offsets[i] = v;
        cursor[i] = v;
    }
}

// ---------------- scatter edges into CSR: single packed 8B store ----------------
__global__ __launch_bounds__(256) void scatter_kernel(
    const int* __restrict__ src, const int* __restrict__ dst,
    const float* __restrict__ e_l, const float* __restrict__ e_r,
    int* __restrict__ cursor, float2* __restrict__ packed)
{
    int e = blockIdx.x * 256 + threadIdx.x;
    if (e >= NE) return;
    int d = dst[e];
    int s = src[e];
    float a = e_l[d] + e_r[s];
    a = (a > 0.f) ? a : NEG_SLOPE * a;
    float w = __expf(a);                 // no max-shift: |a| small, exp safe in fp32
    int pos = atomicAdd(&cursor[d], 1);  // absolute position (cursor seeded with offsets)
    packed[pos] = make_float2(__int_as_float(s), w);
}

// ---------------- softmax-normalize + aggregate ----------------
// one wave per dst node; lane l covers channels (l&15)*4..+3 of edge j+(l>>4):
// one float4 gather instruction fetches FOUR edges' h-rows (1 KB).
__global__ __launch_bounds__(256) void aggregate_kernel(
    const float* __restrict__ h, const int* __restrict__ offsets,
    const float2* __restrict__ packed, const float* __restrict__ bias,
    float* __restrict__ out)
{
    const int node = blockIdx.x * 4 + (threadIdx.x >> 6);
    const int lane = threadIdx.x & 63;
    if (node >= NN) return;
    const int start = offsets[node];
    const int end = offsets[node + 1];
    const int grp = lane >> 4;       // which of 4 edges in the group
    const int ch4 = (lane & 15) * 4; // channel base

    float4 acc = make_float4(0.f, 0.f, 0.f, 0.f);
    float wsum = 0.f;

#pragma unroll 2
    for (int j = start; j < end; j += 4) {
        int eidx = j + grp;
        int ej = (eidx < end) ? eidx : end - 1;   // clamp: no OOB
        float2 p = packed[ej];
        int s = __float_as_int(p.x);
        float w = (eidx < end) ? p.y : 0.f;
        float4 hv = *(const float4*)&h[(size_t)s * OC + ch4];
        wsum += w;
        acc.x += w * hv.x;
        acc.y += w * hv.y;
        acc.z += w * hv.z;
        acc.w += w * hv.w;
    }

    // combine the 4 edge-subgroups (each edge counted once in exactly one subgroup)
#pragma unroll
    for (int m = 16; m <= 32; m <<= 1) {
        acc.x += __shfl_xor(acc.x, m);
        acc.y += __shfl_xor(acc.y, m);
        acc.z += __shfl_xor(acc.z, m);
        acc.w += __shfl_xor(acc.w, m);
        wsum += __shfl_xor(wsum, m);
    }

    if (lane < 16) {
        float inv = 1.f / (wsum + EPS_F);
        float4 b = *(const float4*)&bias[ch4];
        float4 o = make_float4(acc.x * inv + b.x, acc.y * inv + b.y,
                               acc.z * inv + b.z, acc.w * inv + b.w);
        *(float4*)&out[(size_t)node * OC + ch4] = o;
    }
}

extern "C" void kernel_launch(void* const* d_in, const int* in_sizes, int n_in,
                              void* d_out, int out_size, void* d_ws, size_t ws_size,
                              hipStream_t stream)
{
    const float* x = (const float*)d_in[0];
    const int* edge_index = (const int*)d_in[1];
    const float* W = (const float*)d_in[2];
    const float* a_l = (const float*)d_in[3];
    const float* a_r = (const float*)d_in[4];
    const float* bias = (const float*)d_in[5];
    float* out = (float*)d_out;

    const int* src = edge_index;       // row 0
    const int* dst = edge_index + NE;  // row 1

    // workspace layout (keep packed array 8B-aligned)
    char* w = (char*)d_ws;
    float* h = (float*)w;                      // NN*OC
    size_t off = (size_t)NN * OC * 4;
    float* e_l = (float*)(w + off); off += (size_t)NN * 4;
    float* e_r = (float*)(w + off); off += (size_t)NN * 4;
    int* deg = (int*)(w + off);     off += (size_t)NN * 4;
    int* cursor = (int*)(w + off);  off += (size_t)NN * 4;
    int* offsets = (int*)(w + off); off += (size_t)(NN + 2) * 4;  // +2 keeps 8B align
    int* bsums = (int*)(w + off);   off += 128 * 4;
    float2* packed = (float2*)(w + off); off += (size_t)(NE + 8) * 8;

    hipMemsetAsync(deg, 0, (size_t)NN * 4, stream);

    linear_kernel<<<(NN + 63) / 64, 256, 0, stream>>>(x, W, h);
    ev_kernel<<<(NN + 3) / 4, 256, 0, stream>>>(h, a_l, a_r, e_l, e_r);
    degree_kernel<<<(NE / 4 + 255) / 256, 256, 0, stream>>>(dst, deg);
    scan_block_kernel<<<(NN + 1023) / 1024, 1024, 0, stream>>>(deg, offsets, bsums);
    scan_bsums_kernel<<<1, 128, 0, stream>>>(bsums, offsets);
    scan_add_kernel<<<(NN + 1023) / 1024, 1024, 0, stream>>>(offsets, bsums, cursor);
    scatter_kernel<<<(NE + 255) / 256, 256, 0, stream>>>(src, dst, e_l, e_r, cursor, packed);
    aggregate_kernel<<<(NN + 3) / 4, 256, 0, stream>>>(h, offsets, packed, bias, out);
}

// Round 4
// 325.366 us; speedup vs baseline: 2.0205x; 1.1071x over previous
//
#include <hip/hip_runtime.h>
#include <math.h>

#define NN 100000
#define NE 1600000
#define IC 128
#define OC 64
#define NEG_SLOPE 0.2f
#define EPS_F 1e-10f

// Swizzled LDS word index for a [row][128-float] tile stored as 32 float4 chunks/row.
__device__ __forceinline__ int swz(int row, int c4) {
    return row * 128 + (((c4 ^ (row >> 2)) & 31) << 2);
}

__device__ __forceinline__ unsigned short f2bf(float f) {  // RNE
    unsigned u = __float_as_uint(f);
    u += 0x7fff + ((u >> 16) & 1);
    return (unsigned short)(u >> 16);
}

// ---------------- h = x @ W^T (bf16 out) + fused e_l/e_r (exact fp32) ----------------
__global__ __launch_bounds__(256) void linear_kernel(
    const float* __restrict__ x, const float* __restrict__ W,
    const float* __restrict__ a_l, const float* __restrict__ a_r,
    unsigned short* __restrict__ h_bf, float* __restrict__ e_l,
    float* __restrict__ e_r)
{
    __shared__ float Ws[64 * 128];
    __shared__ float xs[64 * 128];
    const int tid = threadIdx.x;
    const int n0 = blockIdx.x * 64;

#pragma unroll
    for (int it = 0; it < 8; it++) {
        int idx4 = it * 256 + tid;
        int r = idx4 >> 5, c4 = idx4 & 31;
        float4 wv = *(const float4*)&W[r * 128 + (c4 << 2)];
        *(float4*)&Ws[swz(r, c4)] = wv;
        int n = n0 + r;
        float4 xv = make_float4(0.f, 0.f, 0.f, 0.f);
        if (n < NN) xv = *(const float4*)&x[(size_t)n * 128 + (c4 << 2)];
        *(float4*)&xs[swz(r, c4)] = xv;
    }
    __syncthreads();

    const int og = tid >> 4;   // oc base og*4
    const int ng = tid & 15;   // node base ng*4
    float acc[4][4];
#pragma unroll
    for (int i = 0; i < 4; i++)
#pragma unroll
        for (int j = 0; j < 4; j++) acc[i][j] = 0.f;

#pragma unroll 4
    for (int k4 = 0; k4 < 32; k4++) {
        float4 wv[4], xv[4];
#pragma unroll
        for (int i = 0; i < 4; i++) wv[i] = *(const float4*)&Ws[swz(og * 4 + i, k4)];
#pragma unroll
        for (int j = 0; j < 4; j++) xv[j] = *(const float4*)&xs[swz(ng * 4 + j, k4)];
#pragma unroll
        for (int i = 0; i < 4; i++)
#pragma unroll
            for (int j = 0; j < 4; j++) {
                acc[i][j] += wv[i].x * xv[j].x;
                acc[i][j] += wv[i].y * xv[j].y;
                acc[i][j] += wv[i].z * xv[j].z;
                acc[i][j] += wv[i].w * xv[j].w;
            }
    }

    // h store (bf16, 8B per thread per node)
#pragma unroll
    for (int j = 0; j < 4; j++) {
        int n = n0 + ng * 4 + j;
        if (n < NN) {
            ushort4 hv;
            hv.x = f2bf(acc[0][j]); hv.y = f2bf(acc[1][j]);
            hv.z = f2bf(acc[2][j]); hv.w = f2bf(acc[3][j]);
            *(ushort4*)&h_bf[(size_t)n * OC + og * 4] = hv;
        }
    }

    // fused e_l/e_r: partial dot over this thread's 4 oc, then LDS-reduce over 16 og groups
    float4 al4 = *(const float4*)&a_l[og * 4];
    float4 ar4 = *(const float4*)&a_r[og * 4];
    float elp[4], erp[4];
#pragma unroll
    for (int j = 0; j < 4; j++) {
        elp[j] = al4.x * acc[0][j] + al4.y * acc[1][j] + al4.z * acc[2][j] + al4.w * acc[3][j];
        erp[j] = ar4.x * acc[0][j] + ar4.y * acc[1][j] + ar4.z * acc[2][j] + ar4.w * acc[3][j];
    }
    __syncthreads();                      // done reading Ws/xs; reuse Ws as buffers
    float* elb = Ws;                      // [16][65] padded
    float* erb = Ws + 16 * 65;
#pragma unroll
    for (int j = 0; j < 4; j++) {
        elb[og * 65 + ng * 4 + j] = elp[j];
        erb[og * 65 + ng * 4 + j] = erp[j];
    }
    __syncthreads();
    if (tid < 64) {
        int n = n0 + tid;
        if (n < NN) {
            float el = 0.f, er = 0.f;
#pragma unroll
            for (int g = 0; g < 16; g++) {
                el += elb[g * 65 + tid];
                er += erb[g * 65 + tid];
            }
            e_l[n] = el;
            e_r[n] = er;
        }
    }
}

// ---------------- degree count (int4 loads) ----------------
__global__ __launch_bounds__(256) void degree_kernel(
    const int* __restrict__ dst, int* __restrict__ deg)
{
    int i = blockIdx.x * 256 + threadIdx.x;
    if (i < NE / 4) {
        int4 d = ((const int4*)dst)[i];
        atomicAdd(&deg[d.x], 1);
        atomicAdd(&deg[d.y], 1);
        atomicAdd(&deg[d.z], 1);
        atomicAdd(&deg[d.w], 1);
    }
}

// ---------------- 3-phase multi-block scan ----------------
__global__ __launch_bounds__(1024) void scan_block_kernel(
    const int* __restrict__ deg, int* __restrict__ offsets,
    int* __restrict__ bsums)
{
    __shared__ int s[1024];
    const int t = threadIdx.x;
    const int i = blockIdx.x * 1024 + t;
    int v = (i < NN) ? deg[i] : 0;
    s[t] = v;
    __syncthreads();
    for (int off = 1; off < 1024; off <<= 1) {
        int u = (t >= off) ? s[t - off] : 0;
        __syncthreads();
        s[t] += u;
        __syncthreads();
    }
    if (i < NN) offsets[i] = s[t] - v;
    if (t == 1023) bsums[blockIdx.x] = s[1023];
}

__global__ __launch_bounds__(128) void scan_bsums_kernel(
    int* __restrict__ bsums, int* __restrict__ offsets)
{
    __shared__ int s[128];
    const int t = threadIdx.x;
    const int NB = (NN + 1023) / 1024;
    int v = (t < NB) ? bsums[t] : 0;
    s[t] = v;
    __syncthreads();
    for (int off = 1; off < 128; off <<= 1) {
        int u = (t >= off) ? s[t - off] : 0;
        __syncthreads();
        s[t] += u;
        __syncthreads();
    }
    if (t < NB) bsums[t] = s[t] - v;
    if (t == NB - 1) offsets[NN] = s[t];
}

__global__ __launch_bounds__(1024) void scan_add_kernel(
    int* __restrict__ offsets, const int* __restrict__ bsums,
    int* __restrict__ cursor)
{
    int i = blockIdx.x * 1024 + threadIdx.x;
    if (i < NN) {
        int v = offsets[i] + bsums[blockIdx.x];
        offsets[i] = v;
        cursor[i] = v;
    }
}

// ---------------- XCD-sliced scatter ----------------
// slice = blockIdx&7 (maps round-robin to XCDs). Each slice scans ALL edges but
// keeps only dst in its 1/8 node range -> all its stores land in a contiguous
// ~1.6MB position window resident in its own L2 (full-line write combining).
#define SCAT_BPS 416   // blocks per slice
__global__ __launch_bounds__(256) void scatter_kernel(
    const int* __restrict__ src, const int* __restrict__ dst,
    const float* __restrict__ e_l, const float* __restrict__ e_r,
    int* __restrict__ cursor, float2* __restrict__ packed)
{
    const int slice = blockIdx.x & 7;
    const int lo = slice * (NN / 8);
    const int hi = lo + (NN / 8);
    const int stride = SCAT_BPS * 256;
    for (int g = (blockIdx.x >> 3) * 256 + threadIdx.x; g < NE / 4; g += stride) {
        int4 d4 = ((const int4*)dst)[g];
        int4 s4 = ((const int4*)src)[g];
        int dd[4] = {d4.x, d4.y, d4.z, d4.w};
        int ss[4] = {s4.x, s4.y, s4.z, s4.w};
#pragma unroll
        for (int k = 0; k < 4; k++) {
            int d = dd[k];
            if (d >= lo && d < hi) {
                int s = ss[k];
                float a = e_l[d] + e_r[s];
                a = (a > 0.f) ? a : NEG_SLOPE * a;
                float w = __expf(a);               // |a| small: exp safe in fp32
                int pos = atomicAdd(&cursor[d], 1); // absolute (cursor seeded w/ offsets)
                packed[pos] = make_float2(__int_as_float(s), w);
            }
        }
    }
}

// ---------------- softmax-normalize + aggregate ----------------
// one wave per dst node; 8 lanes per edge, each lane gathers 16B (8 bf16 channels):
// one instruction fetches EIGHT edges' h-rows (1 KB).
__global__ __launch_bounds__(256) void aggregate_kernel(
    const unsigned short* __restrict__ h_bf, const int* __restrict__ offsets,
    const float2* __restrict__ packed, const float* __restrict__ bias,
    float* __restrict__ out)
{
    const int node = blockIdx.x * 4 + (threadIdx.x >> 6);
    const int lane = threadIdx.x & 63;
    if (node >= NN) return;
    const int start = offsets[node];
    const int end = offsets[node + 1];
    const int grp = lane >> 3;        // which of 8 edges in the group
    const int ch = (lane & 7) * 8;    // channel base (8 channels per lane)

    float acc[8] = {0.f, 0.f, 0.f, 0.f, 0.f, 0.f, 0.f, 0.f};
    float wsum = 0.f;

#pragma unroll 2
    for (int j = start; j < end; j += 8) {
        int eidx = j + grp;
        int ej = (eidx < end) ? eidx : end - 1;   // clamp: no OOB
        float2 p = packed[ej];
        float w = (eidx < end) ? p.y : 0.f;
        int s = __float_as_int(p.x);
        uint4 q = *(const uint4*)&h_bf[(size_t)s * OC + ch];
        wsum += w;
        acc[0] += w * __uint_as_float(q.x << 16);
        acc[1] += w * __uint_as_float(q.x & 0xffff0000u);
        acc[2] += w * __uint_as_float(q.y << 16);
        acc[3] += w * __uint_as_float(q.y & 0xffff0000u);
        acc[4] += w * __uint_as_float(q.z << 16);
        acc[5] += w * __uint_as_float(q.z & 0xffff0000u);
        acc[6] += w * __uint_as_float(q.w << 16);
        acc[7] += w * __uint_as_float(q.w & 0xffff0000u);
    }

    // combine the 8 edge-subgroups (each edge counted in exactly one subgroup)
#pragma unroll
    for (int m = 8; m <= 32; m <<= 1) {
#pragma unroll
        for (int k = 0; k < 8; k++) acc[k] += __shfl_xor(acc[k], m);
        wsum += __shfl_xor(wsum, m);
    }

    if (lane < 8) {
        float inv = 1.f / (wsum + EPS_F);
        float4 b0 = *(const float4*)&bias[lane * 8];
        float4 b1 = *(const float4*)&bias[lane * 8 + 4];
        float4 o0 = make_float4(acc[0] * inv + b0.x, acc[1] * inv + b0.y,
                                acc[2] * inv + b0.z, acc[3] * inv + b0.w);
        float4 o1 = make_float4(acc[4] * inv + b1.x, acc[5] * inv + b1.y,
                                acc[6] * inv + b1.z, acc[7] * inv + b1.w);
        *(float4*)&out[(size_t)node * OC + lane * 8] = o0;
        *(float4*)&out[(size_t)node * OC + lane * 8 + 4] = o1;
    }
}

extern "C" void kernel_launch(void* const* d_in, const int* in_sizes, int n_in,
                              void* d_out, int out_size, void* d_ws, size_t ws_size,
                              hipStream_t stream)
{
    const float* x = (const float*)d_in[0];
    const int* edge_index = (const int*)d_in[1];
    const float* W = (const float*)d_in[2];
    const float* a_l = (const float*)d_in[3];
    const float* a_r = (const float*)d_in[4];
    const float* bias = (const float*)d_in[5];
    float* out = (float*)d_out;

    const int* src = edge_index;       // row 0
    const int* dst = edge_index + NE;  // row 1

    // workspace layout (16B-aligned chunks)
    char* w = (char*)d_ws;
    unsigned short* h_bf = (unsigned short*)w;          // NN*OC bf16 = 12.8 MB
    size_t off = (size_t)NN * OC * 2;
    float* e_l = (float*)(w + off); off += (size_t)NN * 4;
    float* e_r = (float*)(w + off); off += (size_t)NN * 4;
    int* deg = (int*)(w + off);     off += (size_t)NN * 4;
    int* cursor = (int*)(w + off);  off += (size_t)NN * 4;
    int* offsets = (int*)(w + off); off += (size_t)(NN + 4) * 4;
    int* bsums = (int*)(w + off);   off += 128 * 4;
    float2* packed = (float2*)(w + off); off += (size_t)NE * 8;

    hipMemsetAsync(deg, 0, (size_t)NN * 4, stream);

    linear_kernel<<<(NN + 63) / 64, 256, 0, stream>>>(x, W, a_l, a_r, h_bf, e_l, e_r);
    degree_kernel<<<(NE / 4 + 255) / 256, 256, 0, stream>>>(dst, deg);
    scan_block_kernel<<<(NN + 1023) / 1024, 1024, 0, stream>>>(deg, offsets, bsums);
    scan_bsums_kernel<<<1, 128, 0, stream>>>(bsums, offsets);
    scan_add_kernel<<<(NN + 1023) / 1024, 1024, 0, stream>>>(offsets, bsums, cursor);
    scatter_kernel<<<8 * SCAT_BPS, 256, 0, stream>>>(src, dst, e_l, e_r, cursor, packed);
    aggregate_kernel<<<(NN + 3) / 4, 256, 0, stream>>>(h_bf, offsets, packed, bias, out);
}

// Round 5
// 254.091 us; speedup vs baseline: 2.5873x; 1.2805x over previous
//
#include <hip/hip_runtime.h>
#include <math.h>

#define NN 100000
#define NE 1600000
#define IC 128
#define OC 64
#define NEG_SLOPE 0.2f
#define EPS_F 1e-10f

// Swizzled LDS word index for a [row][128-float] tile stored as 32 float4 chunks/row.
__device__ __forceinline__ int swz(int row, int c4) {
    return row * 128 + (((c4 ^ (row >> 2)) & 31) << 2);
}

__device__ __forceinline__ unsigned short f2bf(float f) {  // RNE
    unsigned u = __float_as_uint(f);
    u += 0x7fff + ((u >> 16) & 1);
    return (unsigned short)(u >> 16);
}

// ---------------- h = x @ W^T (bf16) + fused e_l/e_r + fused degree/rank ----------------
// Each block also claims 256 edge-quads: atomicAdd per edge gives degree AND the
// edge's rank within its dst segment (stored coalesced). Atomic latency hides
// under the VALU-bound GEMM.
__global__ __launch_bounds__(256) void linear_kernel(
    const float* __restrict__ x, const float* __restrict__ W,
    const float* __restrict__ a_l, const float* __restrict__ a_r,
    const int* __restrict__ dst,
    unsigned short* __restrict__ h_bf, float* __restrict__ e_l,
    float* __restrict__ e_r, int* __restrict__ deg, int* __restrict__ rank)
{
    __shared__ float Ws[64 * 128];
    __shared__ float xs[64 * 128];
    const int tid = threadIdx.x;
    const int n0 = blockIdx.x * 64;

    // issue edge load early
    const int g = blockIdx.x * 256 + tid;     // quad index
    const bool has_e = g < NE / 4;
    int4 d4 = make_int4(0, 0, 0, 0);
    if (has_e) d4 = ((const int4*)dst)[g];

#pragma unroll
    for (int it = 0; it < 8; it++) {
        int idx4 = it * 256 + tid;
        int r = idx4 >> 5, c4 = idx4 & 31;
        float4 wv = *(const float4*)&W[r * 128 + (c4 << 2)];
        *(float4*)&Ws[swz(r, c4)] = wv;
        int n = n0 + r;
        float4 xv = make_float4(0.f, 0.f, 0.f, 0.f);
        if (n < NN) xv = *(const float4*)&x[(size_t)n * 128 + (c4 << 2)];
        *(float4*)&xs[swz(r, c4)] = xv;
    }
    __syncthreads();

    // degree + rank (atomics overlap with GEMM below via other waves)
    if (has_e) {
        int4 r;
        r.x = atomicAdd(&deg[d4.x], 1);
        r.y = atomicAdd(&deg[d4.y], 1);
        r.z = atomicAdd(&deg[d4.z], 1);
        r.w = atomicAdd(&deg[d4.w], 1);
        ((int4*)rank)[g] = r;
    }

    const int og = tid >> 4;   // oc base og*4
    const int ng = tid & 15;   // node base ng*4
    float acc[4][4];
#pragma unroll
    for (int i = 0; i < 4; i++)
#pragma unroll
        for (int j = 0; j < 4; j++) acc[i][j] = 0.f;

#pragma unroll 4
    for (int k4 = 0; k4 < 32; k4++) {
        float4 wv[4], xv[4];
#pragma unroll
        for (int i = 0; i < 4; i++) wv[i] = *(const float4*)&Ws[swz(og * 4 + i, k4)];
#pragma unroll
        for (int j = 0; j < 4; j++) xv[j] = *(const float4*)&xs[swz(ng * 4 + j, k4)];
#pragma unroll
        for (int i = 0; i < 4; i++)
#pragma unroll
            for (int j = 0; j < 4; j++) {
                acc[i][j] += wv[i].x * xv[j].x;
                acc[i][j] += wv[i].y * xv[j].y;
                acc[i][j] += wv[i].z * xv[j].z;
                acc[i][j] += wv[i].w * xv[j].w;
            }
    }

    // h store (bf16)
#pragma unroll
    for (int j = 0; j < 4; j++) {
        int n = n0 + ng * 4 + j;
        if (n < NN) {
            ushort4 hv;
            hv.x = f2bf(acc[0][j]); hv.y = f2bf(acc[1][j]);
            hv.z = f2bf(acc[2][j]); hv.w = f2bf(acc[3][j]);
            *(ushort4*)&h_bf[(size_t)n * OC + og * 4] = hv;
        }
    }

    // fused e_l/e_r (exact fp32): partial dot over 4 oc, LDS-reduce over 16 groups
    float4 al4 = *(const float4*)&a_l[og * 4];
    float4 ar4 = *(const float4*)&a_r[og * 4];
    float elp[4], erp[4];
#pragma unroll
    for (int j = 0; j < 4; j++) {
        elp[j] = al4.x * acc[0][j] + al4.y * acc[1][j] + al4.z * acc[2][j] + al4.w * acc[3][j];
        erp[j] = ar4.x * acc[0][j] + ar4.y * acc[1][j] + ar4.z * acc[2][j] + ar4.w * acc[3][j];
    }
    __syncthreads();                      // done with Ws/xs; reuse as buffers
    float* elb = Ws;                      // [16][65] padded
    float* erb = Ws + 16 * 65;
#pragma unroll
    for (int j = 0; j < 4; j++) {
        elb[og * 65 + ng * 4 + j] = elp[j];
        erb[og * 65 + ng * 4 + j] = erp[j];
    }
    __syncthreads();
    if (tid < 64) {
        int n = n0 + tid;
        if (n < NN) {
            float el = 0.f, er = 0.f;
#pragma unroll
            for (int gg = 0; gg < 16; gg++) {
                el += elb[gg * 65 + tid];
                er += erb[gg * 65 + tid];
            }
            e_l[n] = el;
            e_r[n] = er;
        }
    }
}

// ---------------- wave-shuffle block scan (2 barriers) ----------------
__global__ __launch_bounds__(1024) void scan_block_kernel(
    const int* __restrict__ deg, int* __restrict__ offsets,
    int* __restrict__ bsums)
{
    __shared__ int wsum[16];
    const int t = threadIdx.x;
    const int lane = t & 63, wv = t >> 6;
    const int i = blockIdx.x * 1024 + t;
    int v = (i < NN) ? deg[i] : 0;
    int incl = v;
#pragma unroll
    for (int off = 1; off < 64; off <<= 1) {
        int u = __shfl_up(incl, off);
        if (lane >= off) incl += u;
    }
    if (lane == 63) wsum[wv] = incl;
    __syncthreads();
    if (wv == 0 && lane < 16) {
        int s = wsum[lane];
        int si = s;
#pragma unroll
        for (int off = 1; off < 16; off <<= 1) {
            int u = __shfl_up(si, off);
            if (lane >= off) si += u;
        }
        wsum[lane] = si - s;   // exclusive wave prefix
    }
    __syncthreads();
    int excl = incl - v + wsum[wv];
    if (i < NN) offsets[i] = excl;
    if (t == 1023) bsums[blockIdx.x] = excl + v;
}

__global__ __launch_bounds__(128) void scan_bsums_kernel(
    int* __restrict__ bsums, int* __restrict__ offsets)
{
    __shared__ int s[128];
    const int t = threadIdx.x;
    const int NB = (NN + 1023) / 1024;
    int v = (t < NB) ? bsums[t] : 0;
    s[t] = v;
    __syncthreads();
    for (int off = 1; off < 128; off <<= 1) {
        int u = (t >= off) ? s[t - off] : 0;
        __syncthreads();
        s[t] += u;
        __syncthreads();
    }
    if (t < NB) bsums[t] = s[t] - v;
    if (t == NB - 1) offsets[NN] = s[t];
}

__global__ __launch_bounds__(1024) void scan_add_kernel(
    int* __restrict__ offsets, const int* __restrict__ bsums)
{
    int i = blockIdx.x * 1024 + threadIdx.x;
    if (i < NN) offsets[i] += bsums[blockIdx.x];
}

// ---------------- scatter: NO atomics (pos = offsets[d] + rank[e]) ----------------
__global__ __launch_bounds__(256) void scatter_kernel(
    const int* __restrict__ src, const int* __restrict__ dst,
    const int* __restrict__ rank, const int* __restrict__ offsets,
    const float* __restrict__ e_l, const float* __restrict__ e_r,
    float2* __restrict__ packed)
{
    int g = blockIdx.x * 256 + threadIdx.x;
    if (g >= NE / 4) return;
    int4 d4 = ((const int4*)dst)[g];
    int4 s4 = ((const int4*)src)[g];
    int4 r4 = ((const int4*)rank)[g];
    int dd[4] = {d4.x, d4.y, d4.z, d4.w};
    int ss[4] = {s4.x, s4.y, s4.z, s4.w};
    int rr[4] = {r4.x, r4.y, r4.z, r4.w};
#pragma unroll
    for (int k = 0; k < 4; k++) {
        int d = dd[k], s = ss[k];
        float a = e_l[d] + e_r[s];
        a = (a > 0.f) ? a : NEG_SLOPE * a;
        float w = __expf(a);               // |a| small: exp safe in fp32, no max-shift
        packed[offsets[d] + rr[k]] = make_float2(__int_as_float(s), w);
    }
}

// ---------------- softmax-normalize + aggregate ----------------
// one wave per dst node; 8 lanes per edge, each lane gathers 16B (8 bf16 channels).
__global__ __launch_bounds__(256) void aggregate_kernel(
    const unsigned short* __restrict__ h_bf, const int* __restrict__ offsets,
    const float2* __restrict__ packed, const float* __restrict__ bias,
    float* __restrict__ out)
{
    const int node = blockIdx.x * 4 + (threadIdx.x >> 6);
    const int lane = threadIdx.x & 63;
    if (node >= NN) return;
    const int start = offsets[node];
    const int end = offsets[node + 1];
    const int grp = lane >> 3;        // which of 8 edges in the group
    const int ch = (lane & 7) * 8;    // channel base (8 channels per lane)

    float acc[8] = {0.f, 0.f, 0.f, 0.f, 0.f, 0.f, 0.f, 0.f};
    float wsum = 0.f;

#pragma unroll 2
    for (int j = start; j < end; j += 8) {
        int eidx = j + grp;
        int ej = (eidx < end) ? eidx : end - 1;   // clamp: no OOB
        float2 p = packed[ej];
        float w = (eidx < end) ? p.y : 0.f;
        int s = __float_as_int(p.x);
        uint4 q = *(const uint4*)&h_bf[(size_t)s * OC + ch];
        wsum += w;
        acc[0] += w * __uint_as_float(q.x << 16);
        acc[1] += w * __uint_as_float(q.x & 0xffff0000u);
        acc[2] += w * __uint_as_float(q.y << 16);
        acc[3] += w * __uint_as_float(q.y & 0xffff0000u);
        acc[4] += w * __uint_as_float(q.z << 16);
        acc[5] += w * __uint_as_float(q.z & 0xffff0000u);
        acc[6] += w * __uint_as_float(q.w << 16);
        acc[7] += w * __uint_as_float(q.w & 0xffff0000u);
    }

#pragma unroll
    for (int m = 8; m <= 32; m <<= 1) {
#pragma unroll
        for (int k = 0; k < 8; k++) acc[k] += __shfl_xor(acc[k], m);
        wsum += __shfl_xor(wsum, m);
    }

    if (lane < 8) {
        float inv = 1.f / (wsum + EPS_F);
        float4 b0 = *(const float4*)&bias[lane * 8];
        float4 b1 = *(const float4*)&bias[lane * 8 + 4];
        float4 o0 = make_float4(acc[0] * inv + b0.x, acc[1] * inv + b0.y,
                                acc[2] * inv + b0.z, acc[3] * inv + b0.w);
        float4 o1 = make_float4(acc[4] * inv + b1.x, acc[5] * inv + b1.y,
                                acc[6] * inv + b1.z, acc[7] * inv + b1.w);
        *(float4*)&out[(size_t)node * OC + lane * 8] = o0;
        *(float4*)&out[(size_t)node * OC + lane * 8 + 4] = o1;
    }
}

extern "C" void kernel_launch(void* const* d_in, const int* in_sizes, int n_in,
                              void* d_out, int out_size, void* d_ws, size_t ws_size,
                              hipStream_t stream)
{
    const float* x = (const float*)d_in[0];
    const int* edge_index = (const int*)d_in[1];
    const float* W = (const float*)d_in[2];
    const float* a_l = (const float*)d_in[3];
    const float* a_r = (const float*)d_in[4];
    const float* bias = (const float*)d_in[5];
    float* out = (float*)d_out;

    const int* src = edge_index;       // row 0
    const int* dst = edge_index + NE;  // row 1

    // workspace layout (16B-aligned chunks)
    char* w = (char*)d_ws;
    unsigned short* h_bf = (unsigned short*)w;          // NN*OC bf16 = 12.8 MB
    size_t off = (size_t)NN * OC * 2;
    float* e_l = (float*)(w + off); off += (size_t)NN * 4;
    float* e_r = (float*)(w + off); off += (size_t)NN * 4;
    int* deg = (int*)(w + off);     off += (size_t)NN * 4;
    int* offsets = (int*)(w + off); off += (size_t)(NN + 4) * 4;
    int* bsums = (int*)(w + off);   off += 128 * 4;
    int* rank = (int*)(w + off);    off += (size_t)NE * 4;
    float2* packed = (float2*)(w + off); off += (size_t)NE * 8;

    hipMemsetAsync(deg, 0, (size_t)NN * 4, stream);

    linear_kernel<<<(NN + 63) / 64, 256, 0, stream>>>(x, W, a_l, a_r, dst,
                                                      h_bf, e_l, e_r, deg, rank);
    scan_block_kernel<<<(NN + 1023) / 1024, 1024, 0, stream>>>(deg, offsets, bsums);
    scan_bsums_kernel<<<1, 128, 0, stream>>>(bsums, offsets);
    scan_add_kernel<<<(NN + 1023) / 1024, 1024, 0, stream>>>(offsets, bsums);
    scatter_kernel<<<(NE / 4 + 255) / 256, 256, 0, stream>>>(src, dst, rank, offsets,
                                                             e_l, e_r, packed);
    aggregate_kernel<<<(NN + 3) / 4, 256, 0, stream>>>(h_bf, offsets, packed, bias, out);
}